// Round 1
// baseline (189.201 us; speedup 1.0000x reference)
//
#include <hip/hip_runtime.h>
#include <hip/hip_bf16.h>

typedef unsigned short u16;
typedef __attribute__((ext_vector_type(4))) float f32x4;
typedef __attribute__((ext_vector_type(8))) short bf16x8;
typedef __attribute__((ext_vector_type(4))) unsigned int u32x4;
typedef __attribute__((ext_vector_type(8))) unsigned short u16x8;

#define DEV static __device__ __forceinline__

// Shapes
// B=4 L=5 HW=1024 C=256 M=8 D=32 T=2 R=4 INNER=256
// P layout per token row (1280 cols, bf16):
//   [0:256)      k        (m*32+d)
//   [256+tj*256) q2[tj]   tj in {0,1}
//   [768+ti*256) v2[ti]   ti in {0,1}

DEV u16 f2b(float f) {                       // RNE f32->bf16
  unsigned u = __float_as_uint(f);
  u = (u + 0x7FFFu + ((u >> 16) & 1u)) >> 16;
  return (u16)u;
}

// ---------------- x f32 -> bf16 ----------------
__global__ __launch_bounds__(256) void conv_x_kernel(const float* __restrict__ x,
                                                     u16* __restrict__ xb) {
  size_t i = ((size_t)blockIdx.x * 256 + threadIdx.x) * 8;
  f32x4 v0 = *(const f32x4*)(x + i);
  f32x4 v1 = *(const f32x4*)(x + i + 4);
  u16x8 o;
  o[0] = f2b(v0[0]); o[1] = f2b(v0[1]); o[2] = f2b(v0[2]); o[3] = f2b(v0[3]);
  o[4] = f2b(v1[0]); o[5] = f2b(v1[1]); o[6] = f2b(v1[2]); o[7] = f2b(v1[3]);
  *(u16x8*)(xb + i) = o;
}

// ---------------- fold relation mats into projection weights ----------------
// Wbig[t][o][c] (bf16), Bbig[t][o] (f32), o in [0,1280)
//   o<256        : k_w[t][o][c]
//   o in [256,768): tj=(o-256)>>8, q'=(o-256)&255, m=q'>>5, qq=q'&31
//                   sum_p q_w[t][m*32+p][c] * rel_att[t*2+tj][m][p][qq]
//   o in [768,1280): ti=(o-768)>>8, c'=(o-768)&255, m=c'>>5, cc=c'&31
//                   sum_p v_w[t][m*32+p][c] * rel_msg[ti*2+t][m][p][cc]
// plus awb = bf16(a_w)
__global__ __launch_bounds__(256) void prep_w_kernel(
    const float* __restrict__ q_w, const float* __restrict__ q_b,
    const float* __restrict__ k_w, const float* __restrict__ k_b,
    const float* __restrict__ v_w, const float* __restrict__ v_b,
    const float* __restrict__ a_w,
    const float* __restrict__ r_att, const float* __restrict__ r_msg,
    u16* __restrict__ Wbig, float* __restrict__ Bbig, u16* __restrict__ awb) {
  int idx = blockIdx.x * 256 + threadIdx.x;
  const int NW = 2 * 1280 * 256;
  if (idx < NW) {
    int t = idx / (1280 * 256);
    int o = (idx / 256) % 1280;
    int c = idx & 255;
    float val;
    if (o < 256) {
      val = k_w[(size_t)(t * 256 + o) * 256 + c];
      if (c == 0) Bbig[t * 1280 + o] = k_b[t * 256 + o];
    } else if (o < 768) {
      int sec = o - 256, tj = sec >> 8, q_ = sec & 255;
      int mh = q_ >> 5, qq = q_ & 31;
      const float* W = r_att + (size_t)((t * 2 + tj) * 8 + mh) * 1024;
      const float* qwc = q_w + (size_t)(t * 256 + mh * 32) * 256 + c;
      float s = 0.f;
      for (int p = 0; p < 32; p++) s += qwc[p * 256] * W[p * 32 + qq];
      val = s;
      if (c == 0) {
        float sb = 0.f;
        const float* qb = q_b + t * 256 + mh * 32;
        for (int p = 0; p < 32; p++) sb += qb[p] * W[p * 32 + qq];
        Bbig[t * 1280 + o] = sb;
      }
    } else {
      int sec = o - 768, ti = sec >> 8, c_ = sec & 255;
      int mh = c_ >> 5, cc = c_ & 31;
      const float* W = r_msg + (size_t)((ti * 2 + t) * 8 + mh) * 1024;
      const float* vwc = v_w + (size_t)(t * 256 + mh * 32) * 256 + c;
      float s = 0.f;
      for (int p = 0; p < 32; p++) s += vwc[p * 256] * W[p * 32 + cc];
      val = s;
      if (c == 0) {
        float sb = 0.f;
        const float* vb = v_b + t * 256 + mh * 32;
        for (int p = 0; p < 32; p++) sb += vb[p] * W[p * 32 + cc];
        Bbig[t * 1280 + o] = sb;
      }
    }
    Wbig[idx] = f2b(val);
  } else {
    int k = idx - NW;
    if (k < 2 * 256 * 256) awb[k] = f2b(a_w[k]);
  }
}

// ---------------- bf16 GEMM: (1024 x 256) x (256 x NTOT) per (b,l) ----------------
// A[bl][row][256] bf16, Wb[t][o][256] bf16, out row-major [bl][row][NTOT]
template <int NTOT, bool OUT_BF16>
__global__ __launch_bounds__(256) void gemm_kernel(
    const u16* __restrict__ A, const u16* __restrict__ Wb,
    const float* __restrict__ bias, const float* __restrict__ pe,
    void* __restrict__ Out) {
  __shared__ u16 a_lds[64 * 32];
  __shared__ u16 b_lds[64 * 32];
  const int bl = blockIdx.z, rt = blockIdx.y, ct = blockIdx.x;
  const int t = (int)pe[(size_t)bl * 3072 + 2];
  const int tid = threadIdx.x, w = tid >> 6, lane = tid & 63;
  const int wm = w >> 1, wn = w & 1;
  const u16* Ab = A + ((size_t)bl * 1024 + rt * 64) * 256;
  const u16* Bb = Wb + ((size_t)t * NTOT + ct * 64) * 256;
  const size_t soff = (size_t)(w * 16 + (lane >> 2)) * 256 + (lane & 3) * 8;
  f32x4 acc[2][2] = {};

  const int r16 = lane & 15;
  const int kg = (lane >> 4) * 8;

  for (int kk = 0; kk < 8; kk++) {
    const int c0 = kk * 32;
    __builtin_amdgcn_global_load_lds(
        (const __attribute__((address_space(1))) void*)(Ab + soff + c0),
        (__attribute__((address_space(3))) void*)(&a_lds[w * 512]), 16, 0, 0);
    __builtin_amdgcn_global_load_lds(
        (const __attribute__((address_space(1))) void*)(Bb + soff + c0),
        (__attribute__((address_space(3))) void*)(&b_lds[w * 512]), 16, 0, 0);
    asm volatile("s_waitcnt vmcnt(0)" ::: "memory");
    __syncthreads();
    bf16x8 a0 = *(const bf16x8*)&a_lds[(wm * 32 + r16) * 32 + kg];
    bf16x8 a1 = *(const bf16x8*)&a_lds[(wm * 32 + 16 + r16) * 32 + kg];
    bf16x8 b0 = *(const bf16x8*)&b_lds[(wn * 32 + r16) * 32 + kg];
    bf16x8 b1 = *(const bf16x8*)&b_lds[(wn * 32 + 16 + r16) * 32 + kg];
    acc[0][0] = __builtin_amdgcn_mfma_f32_16x16x32_bf16(a0, b0, acc[0][0], 0, 0, 0);
    acc[0][1] = __builtin_amdgcn_mfma_f32_16x16x32_bf16(a0, b1, acc[0][1], 0, 0, 0);
    acc[1][0] = __builtin_amdgcn_mfma_f32_16x16x32_bf16(a1, b0, acc[1][0], 0, 0, 0);
    acc[1][1] = __builtin_amdgcn_mfma_f32_16x16x32_bf16(a1, b1, acc[1][1], 0, 0, 0);
    __syncthreads();
  }

  // epilogue: D row=(lane>>4)*4+reg, col=lane&15 (m89-verified)
  #pragma unroll
  for (int mi = 0; mi < 2; mi++)
    #pragma unroll
    for (int ni = 0; ni < 2; ni++) {
      const int col = ct * 64 + wn * 32 + ni * 16 + (lane & 15);
      const float bv = bias[t * NTOT + col];
      #pragma unroll
      for (int rg = 0; rg < 4; rg++) {
        const int row = rt * 64 + wm * 32 + mi * 16 + (lane >> 4) * 4 + rg;
        const float v = acc[mi][ni][rg] + bv;
        const size_t oidx = ((size_t)bl * 1024 + row) * NTOT + col;
        if (OUT_BF16)
          ((u16*)Out)[oidx] = f2b(v);
        else
          ((float*)Out)[oidx] = v;
      }
    }
}

// ---------------- attention: thread-per-row ----------------
DEV void load8(const u16* p, float* f) {
  u32x4 v = *(const u32x4*)p;
  #pragma unroll
  for (int e = 0; e < 4; e++) {
    f[2 * e]     = __uint_as_float(v[e] << 16);
    f[2 * e + 1] = __uint_as_float(v[e] & 0xffff0000u);
  }
}

__global__ __launch_bounds__(64) void attn_kernel(
    const u16* __restrict__ P, const float* __restrict__ mask,
    const float* __restrict__ pe, u16* __restrict__ AO) {
  const int rt = blockIdx.x, m = blockIdx.y, b = blockIdx.z;
  const int r = rt * 64 + threadIdx.x;
  int tl[5];
  #pragma unroll
  for (int l = 0; l < 5; l++) tl[l] = (int)pe[(size_t)(b * 5 + l) * 3072 + 2];
  const float scale = 0.17677669529663687f;  // 1/sqrt(32)
  const u16* rowp[5];
  #pragma unroll
  for (int j = 0; j < 5; j++) rowp[j] = P + ((size_t)(b * 5 + j) * 1024 + r) * 1280;

  float att[5][5] = {};
  #pragma unroll
  for (int ch = 0; ch < 4; ch++) {
    const int d0 = m * 32 + ch * 8;
    float kf[5][8];
    #pragma unroll
    for (int j = 0; j < 5; j++) load8(rowp[j] + d0, kf[j]);
    #pragma unroll
    for (int i = 0; i < 5; i++) {
      float qa[8], qb[8];
      load8(rowp[i] + 256 + d0, qa);
      load8(rowp[i] + 512 + d0, qb);
      #pragma unroll
      for (int j = 0; j < 5; j++) {
        float s = 0.f;
        if (tl[j]) {
          #pragma unroll
          for (int e = 0; e < 8; e++) s += qb[e] * kf[j][e];
        } else {
          #pragma unroll
          for (int e = 0; e < 8; e++) s += qa[e] * kf[j][e];
        }
        att[i][j] += s;
      }
    }
  }

  const float* mrow = mask + ((size_t)b * 1024 + r) * 25;
  float p[5][5];
  #pragma unroll
  for (int i = 0; i < 5; i++) {
    float mx = -1e30f, a_[5];
    #pragma unroll
    for (int j = 0; j < 5; j++) {
      float a = att[i][j] * scale;
      if (mrow[i * 5 + j] == 0.f) a = -1e30f;
      a_[j] = a;
      mx = fmaxf(mx, a);
    }
    float s = 0.f;
    #pragma unroll
    for (int j = 0; j < 5; j++) {
      float e = __expf(a_[j] - mx);
      p[i][j] = e;
      s += e;
    }
    const float inv = 1.f / s;
    #pragma unroll
    for (int j = 0; j < 5; j++) p[i][j] *= inv;
  }

  #pragma unroll
  for (int ch = 0; ch < 4; ch++) {
    const int d0 = m * 32 + ch * 8;
    float acc[5][8] = {};
    #pragma unroll
    for (int j = 0; j < 5; j++) {
      float va[8], vb[8];
      load8(rowp[j] + 768 + d0, va);
      load8(rowp[j] + 1024 + d0, vb);
      #pragma unroll
      for (int i = 0; i < 5; i++) {
        const float pij = p[i][j];
        if (tl[i]) {
          #pragma unroll
          for (int e = 0; e < 8; e++) acc[i][e] += pij * vb[e];
        } else {
          #pragma unroll
          for (int e = 0; e < 8; e++) acc[i][e] += pij * va[e];
        }
      }
    }
    #pragma unroll
    for (int i = 0; i < 5; i++) {
      u16x8 o;
      #pragma unroll
      for (int e = 0; e < 8; e++) o[e] = f2b(acc[i][e]);
      *(u16x8*)(AO + ((size_t)(b * 5 + i) * 1024 + r) * 256 + d0) = o;
    }
  }
}

// ---------------- launch ----------------
extern "C" void kernel_launch(void* const* d_in, const int* in_sizes, int n_in,
                              void* d_out, int out_size, void* d_ws, size_t ws_size,
                              hipStream_t stream) {
  const float* x     = (const float*)d_in[0];
  const float* mask  = (const float*)d_in[1];
  const float* pe    = (const float*)d_in[2];
  const float* q_w   = (const float*)d_in[3];
  const float* q_b   = (const float*)d_in[4];
  const float* k_w   = (const float*)d_in[5];
  const float* k_b   = (const float*)d_in[6];
  const float* v_w   = (const float*)d_in[7];
  const float* v_b   = (const float*)d_in[8];
  const float* a_w   = (const float*)d_in[9];
  const float* a_b   = (const float*)d_in[10];
  const float* r_att = (const float*)d_in[11];
  const float* r_msg = (const float*)d_in[12];

  char* ws = (char*)d_ws;
  u16*   xb   = (u16*)(ws + 0);           // 20480*256 bf16   = 10,485,760 B
  u16*   P    = (u16*)(ws + 10485760);    // 20480*1280 bf16  = 52,428,800 B
  u16*   AO   = (u16*)(ws + 62914560);    // 20480*256 bf16   = 10,485,760 B
  u16*   Wbig = (u16*)(ws + 73400320);    // 2*1280*256 bf16  =  1,310,720 B
  float* Bbig = (float*)(ws + 74711040);  // 2*1280 f32       =     10,240 B
  u16*   awb  = (u16*)(ws + 74721280);    // 2*256*256 bf16   =    262,144 B

  conv_x_kernel<<<dim3(2560), dim3(256), 0, stream>>>(x, xb);
  prep_w_kernel<<<dim3(3072), dim3(256), 0, stream>>>(q_w, q_b, k_w, k_b, v_w, v_b,
                                                      a_w, r_att, r_msg, Wbig, Bbig, awb);
  gemm_kernel<1280, true><<<dim3(20, 16, 20), dim3(256), 0, stream>>>(xb, Wbig, Bbig, pe, (void*)P);
  attn_kernel<<<dim3(16, 8, 4), dim3(64), 0, stream>>>(P, mask, pe, AO);
  gemm_kernel<256, false><<<dim3(4, 16, 20), dim3(256), 0, stream>>>(AO, awb, a_b, pe, d_out);
}